// Round 9
// baseline (235.936 us; speedup 1.0000x reference)
//
#include <hip/hip_runtime.h>
#include <hip/hip_fp16.h>
#include <math.h>

// EnvironmentLight IBL shade, R9.
// 1 pt/thread (TLP wins: R2/R8 multi-point both regressed via VGPR cliff).
// __launch_bounds__(256,8): cap VGPR at 64 -> 8 waves/SIMD AND batch all 4
// scattered dwordx4 loads in one vmcnt window (R8 quad1 @32 VGPR serialized).
// Quad-packed textures (4xRGB9E5 / 4xhalf2) from R6; fused repack from R7.

typedef unsigned int u32;

// ---------------- RGB9E5 ----------------
__device__ __forceinline__ u32 enc9e5(float r, float g, float b) {
    r = fminf(fmaxf(r, 0.f), 65408.f);
    g = fminf(fmaxf(g, 0.f), 65408.f);
    b = fminf(fmaxf(b, 0.f), 65408.f);
    float maxc = fmaxf(r, fmaxf(g, b));
    int e = ((__float_as_int(maxc) >> 23) & 0xff) - 127;
    int exp_p = max(e + 16, 0);
    float denom = __int_as_float((exp_p + 103) << 23);   // 2^(exp_p-24)
    int maxm = (int)(maxc / denom + 0.5f);
    if (maxm == 512) { exp_p += 1; denom *= 2.f; }
    float rd = 1.f / denom;
    u32 rm = (u32)(r * rd + 0.5f);
    u32 gm = (u32)(g * rd + 0.5f);
    u32 bm = (u32)(b * rd + 0.5f);
    return rm | (gm << 9) | (bm << 18) | ((u32)exp_p << 27);
}

__device__ __forceinline__ void dec9e5_acc(u32 pk, float w, float& r, float& g, float& b) {
    float scale = __int_as_float((int)(((pk >> 27) & 31u) + 103u) << 23) * w;
    r += (float)(pk & 511u) * scale;
    g += (float)((pk >> 9) & 511u) * scale;
    b += (float)((pk >> 18) & 511u) * scale;
}

__device__ __forceinline__ void gather_q9(uint4 q, float tx, float ty,
                                          float& r, float& g, float& b) {
    float w01 = tx * (1.f - ty);
    float w00 = (1.f - tx) * (1.f - ty);
    float w10 = (1.f - tx) * ty;
    float w11 = tx * ty;
    r = 0.f; g = 0.f; b = 0.f;
    dec9e5_acc(q.x, w00, r, g, b);
    dec9e5_acc(q.y, w01, r, g, b);
    dec9e5_acc(q.z, w10, r, g, b);
    dec9e5_acc(q.w, w11, r, g, b);
}

__device__ __forceinline__ float srgb1(float x) {
    float p = 1.055f * __builtin_amdgcn_exp2f(
                  __builtin_amdgcn_logf(fmaxf(x, 0.0031308f)) * (1.0f / 2.4f)) - 0.055f;
    return (x <= 0.0031308f) ? (12.92f * x) : p;
}

// face + uv for a direction (shared across levels)
__device__ __forceinline__ void cube_face_uv(float dx, float dy, float dz,
                                             int& face, float& u, float& v) {
    float ax = fabsf(dx), ay = fabsf(dy), az = fabsf(dz);
    bool is_x = (ax >= ay) && (ax >= az);
    bool is_y = (!is_x) && (ay >= az);
    face = is_x ? (dx > 0.f ? 0 : 1)
                : (is_y ? (dy > 0.f ? 2 : 3) : (dz > 0.f ? 4 : 5));
    float ma = fmaxf(is_x ? ax : (is_y ? ay : az), 1e-20f);
    float uu = is_x ? (dx > 0.f ? -dz : dz) : (is_y ? dx : (dz > 0.f ? dx : -dx));
    float vv = is_y ? (dy > 0.f ? dz : -dz) : -dy;
    float inv = __builtin_amdgcn_rcpf(ma);
    u = uu * inv;
    v = vv * inv;
}

// ---------------- layout constants ----------------
#define SPEC_TOTAL 2096640
#define DIF_OFF    SPEC_TOTAL            // 1536 diffuse quads
#define LUT_OFF    (SPEC_TOTAL + 1536)   // 65536 lut quads
#define ALL_QUADS  (SPEC_TOTAL + 1536 + 65536)

// ---------------- fused repack kernel ----------------
__global__ __launch_bounds__(256)
void repack_all(const float* __restrict__ s0, const float* __restrict__ s1,
                const float* __restrict__ s2, const float* __restrict__ s3,
                const float* __restrict__ s4, const float* __restrict__ s5,
                const float* __restrict__ diffuse_map,
                const float2* __restrict__ lut,
                uint4* __restrict__ dst)
{
    int i = blockIdx.x * blockDim.x + threadIdx.x;
    if (i >= ALL_QUADS) return;

    if (i >= LUT_OFF) {
        int k = i - LUT_OFF;
        int y = k >> 8, x = k & 255;
        int x1 = min(x + 1, 255), y1 = min(y + 1, 255);
        float2 c00 = lut[(y << 8) + x],  c01 = lut[(y << 8) + x1];
        float2 c10 = lut[(y1 << 8) + x], c11 = lut[(y1 << 8) + x1];
        __half2 h00 = __floats2half2_rn(c00.x, c00.y);
        __half2 h01 = __floats2half2_rn(c01.x, c01.y);
        __half2 h10 = __floats2half2_rn(c10.x, c10.y);
        __half2 h11 = __floats2half2_rn(c11.x, c11.y);
        uint4 q;
        q.x = *reinterpret_cast<u32*>(&h00);
        q.y = *reinterpret_cast<u32*>(&h01);
        q.z = *reinterpret_cast<u32*>(&h10);
        q.w = *reinterpret_cast<u32*>(&h11);
        dst[i] = q;
        return;
    }

    const float* src;
    int lr, local;
    if (i >= DIF_OFF)       { src = diffuse_map; lr = 4; local = i - DIF_OFF; }
    else if (i < 1572864)   { src = s0; lr = 9; local = i; }
    else if (i < 1966080)   { src = s1; lr = 8; local = i - 1572864; }
    else if (i < 2064384)   { src = s2; lr = 7; local = i - 1966080; }
    else if (i < 2088960)   { src = s3; lr = 6; local = i - 2064384; }
    else if (i < 2095104)   { src = s4; lr = 5; local = i - 2088960; }
    else                    { src = s5; lr = 4; local = i - 2095104; }

    int W = 1 << lr;
    int face = local >> (2 * lr);
    int rem = local & (W * W - 1);
    int y = rem >> lr, x = rem & (W - 1);
    int x1 = min(x + 1, W - 1), y1 = min(y + 1, W - 1);
    int base = face << (2 * lr);
    int i00 = 3 * (base + (y << lr) + x);
    int i01 = 3 * (base + (y << lr) + x1);
    int i10 = 3 * (base + (y1 << lr) + x);
    int i11 = 3 * (base + (y1 << lr) + x1);
    uint4 q;
    q.x = enc9e5(src[i00], src[i00 + 1], src[i00 + 2]);
    q.y = enc9e5(src[i01], src[i01 + 1], src[i01 + 2]);
    q.z = enc9e5(src[i10], src[i10 + 1], src[i10 + 2]);
    q.w = enc9e5(src[i11], src[i11 + 1], src[i11 + 2]);
    dst[i] = q;
}

// ---------------- main kernel ----------------
__global__ __launch_bounds__(256, 8)
void envlight_q1(const float* __restrict__ view_dir,
                 const float* __restrict__ normal,
                 const float* __restrict__ kd,
                 const float* __restrict__ ks,
                 const float* __restrict__ reflect_occ,
                 const uint4* __restrict__ q,
                 float* __restrict__ out, int n)
{
    int i = blockIdx.x * blockDim.x + threadIdx.x;
    if (i >= n) return;

    // --- streaming loads needed for addressing ---
    float vx = view_dir[3 * i + 0], vy = view_dir[3 * i + 1], vz = view_dir[3 * i + 2];
    float nx = normal[3 * i + 0],  ny = normal[3 * i + 1],  nz = normal[3 * i + 2];
    float rough = ks[3 * i + 1];

    // reflect + normalize
    float vdotn = vx * nx + vy * ny + vz * nz;
    float rx = 2.f * vdotn * nx - vx;
    float ry = 2.f * vdotn * ny - vy;
    float rz = 2.f * vdotn * nz - vz;
    float rlen2 = fmaxf(rx * rx + ry * ry + rz * rz, 1e-20f);
    float rinv = __builtin_amdgcn_rsqf(rlen2);
    rx *= rinv; ry *= rinv; rz *= rinv;

    // --- diffuse address (lr=4) ---
    float dtx, dty; int dIdx;
    {
        int face; float u, v;
        cube_face_uv(nx, ny, nz, face, u, v);
        float fx = (u * 0.5f + 0.5f) * 16.f - 0.5f;
        float fy = (v * 0.5f + 0.5f) * 16.f - 0.5f;
        float x0f = floorf(fx), y0f = floorf(fy);
        dtx = fx - x0f; dty = fy - y0f;
        int x0 = min(max((int)x0f, 0), 15);
        int y0 = min(max((int)y0f, 0), 15);
        dIdx = (face << 8) + (y0 << 4) + x0;
    }

    // --- LUT address ---
    float ltx, lty; int lutI;
    {
        float NdotV = fmaxf(vdotn, 1e-4f);
        float fx = NdotV * 256.f - 0.5f;
        float fy = rough * 256.f - 0.5f;
        float x0f = floorf(fx), y0f = floorf(fy);
        ltx = fx - x0f; lty = fy - y0f;
        int x0 = min(max((int)x0f, 0), 255);
        int y0 = min(max((int)y0f, 0), 255);
        lutI = (y0 << 8) + x0;
    }

    // --- mip selection ---
    const float MINR = 0.08f, MAXR = 0.5f;
    float lo = (fminf(fmaxf(rough, MINR), MAXR) - MINR) * (4.0f / (MAXR - MINR));
    float hi = (fminf(fmaxf(rough, MAXR), 1.0f) - MAXR) * (1.0f / (1.0f - MAXR)) + 4.0f;
    float lvl = (rough < MAXR) ? lo : hi;
    lvl = fminf(fmaxf(lvl, 0.f), 5.f);
    int l0 = min(max((int)floorf(lvl), 0), 5);
    int l1 = min(l0 + 1, 5);
    float fmip = lvl - (float)l0;

    // --- spec A address (full), spec B derived (half-res coords, same face) ---
    float atx, aty, btx, bty; int aIdx, bIdx;
    {
        int face; float u, v;
        cube_face_uv(rx, ry, rz, face, u, v);
        int lrA = 9 - l0, lrB = 9 - l1;
        float RA = (float)(1 << lrA);
        float fxA = (u * 0.5f + 0.5f) * RA - 0.5f;
        float fyA = (v * 0.5f + 0.5f) * RA - 0.5f;
        // B coords: same-face, half resolution (or same when l0==l1==5)
        float fxB = (l0 == l1) ? fxA : (fxA + 0.5f) * 0.5f - 0.5f;
        float fyB = (l0 == l1) ? fyA : (fyA + 0.5f) * 0.5f - 0.5f;

        float x0fA = floorf(fxA), y0fA = floorf(fyA);
        atx = fxA - x0fA; aty = fyA - y0fA;
        int WA = 1 << lrA;
        int x0A = min(max((int)x0fA, 0), WA - 1);
        int y0A = min(max((int)y0fA, 0), WA - 1);
        aIdx = (face << (2 * lrA)) + (y0A << lrA) + x0A;

        float x0fB = floorf(fxB), y0fB = floorf(fyB);
        btx = fxB - x0fB; bty = fyB - y0fB;
        int WB = 1 << lrB;
        int x0B = min(max((int)x0fB, 0), WB - 1);
        int y0B = min(max((int)y0fB, 0), WB - 1);
        bIdx = (face << (2 * lrB)) + (y0B << lrB) + x0B;
    }

    static const int OFF[6] = {0, 1572864, 1966080, 2064384, 2088960, 2095104};
    const uint4* tA = q + OFF[l0];
    const uint4* tB = q + OFF[l1];

    // --- issue ALL scattered loads (one vmcnt batch) ---
    uint4 qA = tA[aIdx];
    uint4 qB = tB[bIdx];
    uint4 lq = (q + LUT_OFF)[lutI];
    uint4 dq = (q + DIF_OFF)[dIdx];

    // --- independent streaming loads overlap the scattered latency ---
    float kdx = kd[3 * i + 0], kdy = kd[3 * i + 1], kdz = kd[3 * i + 2];
    float ks0 = ks[3 * i + 0], metallic = ks[3 * i + 2];
    float occ = reflect_occ[i];

    // --- decode + combine ---
    float ar, ag, ab_, br, bg, bb;
    gather_q9(qA, atx, aty, ar, ag, ab_);
    gather_q9(qB, btx, bty, br, bg, bb);

    __half2 h00 = *reinterpret_cast<__half2*>(&lq.x);
    __half2 h01 = *reinterpret_cast<__half2*>(&lq.y);
    __half2 h10 = *reinterpret_cast<__half2*>(&lq.z);
    __half2 h11 = *reinterpret_cast<__half2*>(&lq.w);
    float2 c00 = __half22float2(h00), c01 = __half22float2(h01);
    float2 c10 = __half22float2(h10), c11 = __half22float2(h11);
    float lw00 = (1.f - ltx) * (1.f - lty);
    float lw01 = ltx * (1.f - lty);
    float lw10 = (1.f - ltx) * lty;
    float lw11 = ltx * lty;
    float fg0 = c00.x * lw00 + c01.x * lw01 + c10.x * lw10 + c11.x * lw11;
    float fg1 = c00.y * lw00 + c01.y * lw01 + c10.y * lw10 + c11.y * lw11;

    float dfr, dfg, dfb;
    gather_q9(dq, dtx, dty, dfr, dfg, dfb);
    dfr = fmaxf(dfr, 0.f); dfg = fmaxf(dfg, 0.f); dfb = fmaxf(dfb, 0.f);

    float spr = fmaxf(ar * (1.f - fmip) + br * fmip, 0.f);
    float spg = fmaxf(ag * (1.f - fmip) + bg * fmip, 0.f);
    float spb = fmaxf(ab_ * (1.f - fmip) + bb * fmip, 0.f);

    float m = metallic;
    float scx = (1.f - m) * 0.04f + kdx * m;
    float scy = (1.f - m) * 0.04f + kdy * m;
    float scz = (1.f - m) * 0.04f + kdz * m;
    float dcx = kdx * (1.f - m);
    float dcy = kdy * (1.f - m);
    float dcz = kdz * (1.f - m);

    float kds = 1.f - ks0;
    float shx = dfr * dcx * kds;
    float shy = dfg * dcy * kds;
    float shz = dfb * dcz * kds;

    float om = 1.f - occ;
    shx += spr * (scx * fg0 + fg1) * om;
    shy += spg * (scy * fg0 + fg1) * om;
    shz += spb * (scz * fg0 + fg1) * om;

    out[3 * i + 0] = srgb1(fminf(fmaxf(shx, 0.f), 1.f));
    out[3 * i + 1] = srgb1(fminf(fmaxf(shy, 0.f), 1.f));
    out[3 * i + 2] = srgb1(fminf(fmaxf(shz, 0.f), 1.f));
}

// ---------------- raw-float fallback (ws too small; shouldn't trigger) ----------------
__global__ __launch_bounds__(256)
void envlight_raw(const float* __restrict__ view_dir,
                  const float* __restrict__ normal,
                  const float* __restrict__ kd,
                  const float* __restrict__ ks,
                  const float* __restrict__ reflect_occ,
                  const float* __restrict__ diffuse_map,
                  const float* __restrict__ s0, const float* __restrict__ s1,
                  const float* __restrict__ s2, const float* __restrict__ s3,
                  const float* __restrict__ s4, const float* __restrict__ s5,
                  const float* __restrict__ fg_lut,
                  float* __restrict__ out, int n)
{
    int i = blockIdx.x * blockDim.x + threadIdx.x;
    if (i >= n) return;

    float vx = view_dir[3 * i], vy = view_dir[3 * i + 1], vz = view_dir[3 * i + 2];
    float nx = normal[3 * i],  ny = normal[3 * i + 1],  nz = normal[3 * i + 2];
    float kdx = kd[3 * i], kdy = kd[3 * i + 1], kdz = kd[3 * i + 2];
    float ks0 = ks[3 * i], rough = ks[3 * i + 1], metallic = ks[3 * i + 2];
    float occ = reflect_occ[i];

    float vdotn = vx * nx + vy * ny + vz * nz;
    float rx = 2.f * vdotn * nx - vx;
    float ry = 2.f * vdotn * ny - vy;
    float rz = 2.f * vdotn * nz - vz;
    float rinv = __builtin_amdgcn_rsqf(fmaxf(rx * rx + ry * ry + rz * rz, 1e-20f));
    rx *= rinv; ry *= rinv; rz *= rinv;

    const float* mips[6] = {s0, s1, s2, s3, s4, s5};

    const float MINR = 0.08f, MAXR = 0.5f;
    float lo = (fminf(fmaxf(rough, MINR), MAXR) - MINR) * (4.0f / (MAXR - MINR));
    float hi = (fminf(fmaxf(rough, MAXR), 1.0f) - MAXR) * (1.0f / (1.0f - MAXR)) + 4.0f;
    float lvl = fminf(fmaxf((rough < MAXR) ? lo : hi, 0.f), 5.f);
    int l0 = min(max((int)floorf(lvl), 0), 5);
    int l1 = min(l0 + 1, 5);
    float f = lvl - (float)l0;

    float acc[3][3]; // [which: diff, specA, specB][rgb]
    float dirs[3][3] = {{nx, ny, nz}, {rx, ry, rz}, {rx, ry, rz}};
    int lrs[3] = {4, 9 - l0, 9 - l1};
    const float* texs[3] = {diffuse_map, mips[l0], mips[l1]};
    for (int s = 0; s < 3; ++s) {
        int face; float u, v;
        cube_face_uv(dirs[s][0], dirs[s][1], dirs[s][2], face, u, v);
        int lr = lrs[s], W = 1 << lr;
        float fx = (u * 0.5f + 0.5f) * (float)W - 0.5f;
        float fy = (v * 0.5f + 0.5f) * (float)W - 0.5f;
        float x0f = floorf(fx), y0f = floorf(fy);
        float tx = fx - x0f, ty = fy - y0f;
        int x0 = min(max((int)x0f, 0), W - 1);
        int x1 = min(x0 + 1, W - 1);
        int y0 = min(max((int)y0f, 0), W - 1);
        int y1 = min(y0 + 1, W - 1);
        int base = face << (2 * lr);
        const float* t = texs[s];
        const float* p00 = t + 3 * (base + (y0 << lr) + x0);
        const float* p01 = t + 3 * (base + (y0 << lr) + x1);
        const float* p10 = t + 3 * (base + (y1 << lr) + x0);
        const float* p11 = t + 3 * (base + (y1 << lr) + x1);
        float w00 = (1.f - tx) * (1.f - ty), w01 = tx * (1.f - ty);
        float w10 = (1.f - tx) * ty, w11 = tx * ty;
        for (int c = 0; c < 3; ++c)
            acc[s][c] = p00[c] * w00 + p01[c] * w01 + p10[c] * w10 + p11[c] * w11;
    }

    float NdotV = fmaxf(vdotn, 1e-4f);
    float fx = NdotV * 256.f - 0.5f, fy = rough * 256.f - 0.5f;
    float x0f = floorf(fx), y0f = floorf(fy);
    float tx = fx - x0f, ty = fy - y0f;
    int x0 = min(max((int)x0f, 0), 255);
    int x1 = min(x0 + 1, 255);
    int y0 = min(max((int)y0f, 0), 255);
    int y1 = min(y0 + 1, 255);
    const float2* lut2 = (const float2*)fg_lut;
    float2 c00 = lut2[(y0 << 8) + x0], c01 = lut2[(y0 << 8) + x1];
    float2 c10 = lut2[(y1 << 8) + x0], c11 = lut2[(y1 << 8) + x1];
    float w00 = (1.f - tx) * (1.f - ty), w01 = tx * (1.f - ty);
    float w10 = (1.f - tx) * ty, w11 = tx * ty;
    float fg0 = c00.x * w00 + c01.x * w01 + c10.x * w10 + c11.x * w11;
    float fg1 = c00.y * w00 + c01.y * w01 + c10.y * w10 + c11.y * w11;

    float dfr = fmaxf(acc[0][0], 0.f), dfg = fmaxf(acc[0][1], 0.f), dfb = fmaxf(acc[0][2], 0.f);
    float spr = fmaxf(acc[1][0] * (1.f - f) + acc[2][0] * f, 0.f);
    float spg = fmaxf(acc[1][1] * (1.f - f) + acc[2][1] * f, 0.f);
    float spb = fmaxf(acc[1][2] * (1.f - f) + acc[2][2] * f, 0.f);

    float m = metallic;
    float scx = (1.f - m) * 0.04f + kdx * m;
    float scy = (1.f - m) * 0.04f + kdy * m;
    float scz = (1.f - m) * 0.04f + kdz * m;
    float kds = 1.f - ks0;
    float om = 1.f - occ;
    float shx = dfr * kdx * (1.f - m) * kds + spr * (scx * fg0 + fg1) * om;
    float shy = dfg * kdy * (1.f - m) * kds + spg * (scy * fg0 + fg1) * om;
    float shz = dfb * kdz * (1.f - m) * kds + spb * (scz * fg0 + fg1) * om;

    out[3 * i + 0] = srgb1(fminf(fmaxf(shx, 0.f), 1.f));
    out[3 * i + 1] = srgb1(fminf(fmaxf(shy, 0.f), 1.f));
    out[3 * i + 2] = srgb1(fminf(fmaxf(shz, 0.f), 1.f));
}

extern "C" void kernel_launch(void* const* d_in, const int* in_sizes, int n_in,
                              void* d_out, int out_size, void* d_ws, size_t ws_size,
                              hipStream_t stream) {
    const float* view_dir    = (const float*)d_in[0];
    const float* normal      = (const float*)d_in[1];
    const float* kd          = (const float*)d_in[2];
    const float* ks          = (const float*)d_in[3];
    const float* reflect_occ = (const float*)d_in[4];
    const float* diffuse_map = (const float*)d_in[5];
    const float* s0          = (const float*)d_in[6];
    const float* s1          = (const float*)d_in[7];
    const float* s2          = (const float*)d_in[8];
    const float* s3          = (const float*)d_in[9];
    const float* s4          = (const float*)d_in[10];
    const float* s5          = (const float*)d_in[11];
    const float* fg_lut      = (const float*)d_in[12];
    float* out = (float*)d_out;

    int n = in_sizes[0] / 3;
    int block = 256;
    int grid = (n + block - 1) / block;
    const size_t NEED_Q = (size_t)ALL_QUADS * 16;   // ~34.6 MB

    if (ws_size >= NEED_Q) {
        uint4* q = (uint4*)d_ws;
        repack_all<<<(ALL_QUADS + 255) / 256, 256, 0, stream>>>(
            s0, s1, s2, s3, s4, s5, diffuse_map, (const float2*)fg_lut, q);
        envlight_q1<<<grid, block, 0, stream>>>(
            view_dir, normal, kd, ks, reflect_occ, q, out, n);
    } else {
        envlight_raw<<<grid, block, 0, stream>>>(
            view_dir, normal, kd, ks, reflect_occ, diffuse_map,
            s0, s1, s2, s3, s4, s5, fg_lut, out, n);
    }
}

// Round 10
// 223.304 us; speedup vs baseline: 1.0566x; 1.0566x over previous
//
#include <hip/hip_runtime.h>
#include <hip/hip_fp16.h>
#include <math.h>

// EnvironmentLight IBL shade, R10.
// VMEM-issue-rate bound fix: streaming I/O staged through LDS.
//  - in: 832 float4 coalesced loads/block (3.25/thread) -> LDS -> 13 ds_reads/pt
//  - out: rgb -> LDS -> 192 float4 stores/block (0.75/thread)
//  - scattered: 4 dwordx4/pt (quad-packed textures, R6)
// VMEM instr/pt: 20 -> 8. 1 pt/thread (R2/R8: multi-point = VGPR cliff).
// repack: divide-free enc9e5 (pow2 reciprocal via exponent bits).

typedef unsigned int u32;

// ---------------- RGB9E5 ----------------
__device__ __forceinline__ u32 enc9e5(float r, float g, float b) {
    r = fminf(fmaxf(r, 0.f), 65408.f);
    g = fminf(fmaxf(g, 0.f), 65408.f);
    b = fminf(fmaxf(b, 0.f), 65408.f);
    float maxc = fmaxf(r, fmaxf(g, b));
    int e = ((__float_as_int(maxc) >> 23) & 0xff) - 127;
    int exp_p = max(e + 16, 0);
    float rd = __int_as_float((151 - exp_p) << 23);   // 2^(24-exp_p), exact
    int maxm = (int)(maxc * rd + 0.5f);
    if (maxm == 512) { exp_p += 1; rd *= 0.5f; }
    u32 rm = (u32)(r * rd + 0.5f);
    u32 gm = (u32)(g * rd + 0.5f);
    u32 bm = (u32)(b * rd + 0.5f);
    return rm | (gm << 9) | (bm << 18) | ((u32)exp_p << 27);
}

__device__ __forceinline__ void dec9e5_acc(u32 pk, float w, float& r, float& g, float& b) {
    float scale = __int_as_float((int)(((pk >> 27) & 31u) + 103u) << 23) * w;
    r += (float)(pk & 511u) * scale;
    g += (float)((pk >> 9) & 511u) * scale;
    b += (float)((pk >> 18) & 511u) * scale;
}

__device__ __forceinline__ void gather_q9(uint4 q, float tx, float ty,
                                          float& r, float& g, float& b) {
    float w00 = (1.f - tx) * (1.f - ty);
    float w01 = tx * (1.f - ty);
    float w10 = (1.f - tx) * ty;
    float w11 = tx * ty;
    r = 0.f; g = 0.f; b = 0.f;
    dec9e5_acc(q.x, w00, r, g, b);
    dec9e5_acc(q.y, w01, r, g, b);
    dec9e5_acc(q.z, w10, r, g, b);
    dec9e5_acc(q.w, w11, r, g, b);
}

__device__ __forceinline__ float srgb1(float x) {
    float p = 1.055f * __builtin_amdgcn_exp2f(
                  __builtin_amdgcn_logf(fmaxf(x, 0.0031308f)) * (1.0f / 2.4f)) - 0.055f;
    return (x <= 0.0031308f) ? (12.92f * x) : p;
}

__device__ __forceinline__ void cube_face_uv(float dx, float dy, float dz,
                                             int& face, float& u, float& v) {
    float ax = fabsf(dx), ay = fabsf(dy), az = fabsf(dz);
    bool is_x = (ax >= ay) && (ax >= az);
    bool is_y = (!is_x) && (ay >= az);
    face = is_x ? (dx > 0.f ? 0 : 1)
                : (is_y ? (dy > 0.f ? 2 : 3) : (dz > 0.f ? 4 : 5));
    float ma = fmaxf(is_x ? ax : (is_y ? ay : az), 1e-20f);
    float uu = is_x ? (dx > 0.f ? -dz : dz) : (is_y ? dx : (dz > 0.f ? dx : -dx));
    float vv = is_y ? (dy > 0.f ? dz : -dz) : -dy;
    float inv = __builtin_amdgcn_rcpf(ma);
    u = uu * inv;
    v = vv * inv;
}

// ---------------- layout constants ----------------
#define SPEC_TOTAL 2096640
#define DIF_OFF    SPEC_TOTAL
#define LUT_OFF    (SPEC_TOTAL + 1536)
#define ALL_QUADS  (SPEC_TOTAL + 1536 + 65536)

// ---------------- fused repack kernel ----------------
__global__ __launch_bounds__(256)
void repack_all(const float* __restrict__ s0, const float* __restrict__ s1,
                const float* __restrict__ s2, const float* __restrict__ s3,
                const float* __restrict__ s4, const float* __restrict__ s5,
                const float* __restrict__ diffuse_map,
                const float2* __restrict__ lut,
                uint4* __restrict__ dst)
{
    int i = blockIdx.x * blockDim.x + threadIdx.x;
    if (i >= ALL_QUADS) return;

    if (i >= LUT_OFF) {
        int k = i - LUT_OFF;
        int y = k >> 8, x = k & 255;
        int x1 = min(x + 1, 255), y1 = min(y + 1, 255);
        float2 c00 = lut[(y << 8) + x],  c01 = lut[(y << 8) + x1];
        float2 c10 = lut[(y1 << 8) + x], c11 = lut[(y1 << 8) + x1];
        __half2 h00 = __floats2half2_rn(c00.x, c00.y);
        __half2 h01 = __floats2half2_rn(c01.x, c01.y);
        __half2 h10 = __floats2half2_rn(c10.x, c10.y);
        __half2 h11 = __floats2half2_rn(c11.x, c11.y);
        uint4 q;
        q.x = *reinterpret_cast<u32*>(&h00);
        q.y = *reinterpret_cast<u32*>(&h01);
        q.z = *reinterpret_cast<u32*>(&h10);
        q.w = *reinterpret_cast<u32*>(&h11);
        dst[i] = q;
        return;
    }

    const float* src;
    int lr, local;
    if (i >= DIF_OFF)       { src = diffuse_map; lr = 4; local = i - DIF_OFF; }
    else if (i < 1572864)   { src = s0; lr = 9; local = i; }
    else if (i < 1966080)   { src = s1; lr = 8; local = i - 1572864; }
    else if (i < 2064384)   { src = s2; lr = 7; local = i - 1966080; }
    else if (i < 2088960)   { src = s3; lr = 6; local = i - 2064384; }
    else if (i < 2095104)   { src = s4; lr = 5; local = i - 2088960; }
    else                    { src = s5; lr = 4; local = i - 2095104; }

    int W = 1 << lr;
    int face = local >> (2 * lr);
    int rem = local & (W * W - 1);
    int y = rem >> lr, x = rem & (W - 1);
    int x1 = min(x + 1, W - 1), y1 = min(y + 1, W - 1);
    int base = face << (2 * lr);
    int i00 = 3 * (base + (y << lr) + x);
    int i01 = 3 * (base + (y << lr) + x1);
    int i10 = 3 * (base + (y1 << lr) + x);
    int i11 = 3 * (base + (y1 << lr) + x1);
    uint4 q;
    q.x = enc9e5(src[i00], src[i00 + 1], src[i00 + 2]);
    q.y = enc9e5(src[i01], src[i01 + 1], src[i01 + 2]);
    q.z = enc9e5(src[i10], src[i10 + 1], src[i10 + 2]);
    q.w = enc9e5(src[i11], src[i11 + 1], src[i11 + 2]);
    dst[i] = q;
}

// ---------------- main kernel: LDS-staged streaming I/O ----------------
// LDS float layout: vd[0..767] nm[768..1535] kd[1536..2303] ks[2304..3071]
//                   oc[3072..3327]  => 832 float4.  s_out: 768 floats.
__global__ __launch_bounds__(256, 8)
void envlight_lds(const float* __restrict__ view_dir,
                  const float* __restrict__ normal,
                  const float* __restrict__ kd,
                  const float* __restrict__ ks,
                  const float* __restrict__ reflect_occ,
                  const uint4* __restrict__ q,
                  float* __restrict__ out, int n)
{
    __shared__ float s_in[3328];
    __shared__ float s_out[768];
    int tid = threadIdx.x;
    int base = blockIdx.x << 8;
    int nblk = min(256, n - base);

    if (nblk == 256) {
        const float4* v4 = (const float4*)(view_dir + 3 * base);
        const float4* n4 = (const float4*)(normal + 3 * base);
        const float4* k4 = (const float4*)(kd + 3 * base);
        const float4* q4 = (const float4*)(ks + 3 * base);
        const float4* o4 = (const float4*)(reflect_occ + base);
        float4* dst4 = (float4*)s_in;
        #pragma unroll
        for (int k = 0; k < 4; ++k) {
            int j = tid + (k << 8);
            if (j < 832) {
                const float4* src; int off;
                if (j < 192)      { src = v4; off = j; }
                else if (j < 384) { src = n4; off = j - 192; }
                else if (j < 576) { src = k4; off = j - 384; }
                else if (j < 768) { src = q4; off = j - 576; }
                else              { src = o4; off = j - 768; }
                dst4[j] = src[off];
            }
        }
    } else {
        for (int j = tid; j < nblk * 3; j += 256) {
            s_in[j]        = view_dir[3 * base + j];
            s_in[768 + j]  = normal[3 * base + j];
            s_in[1536 + j] = kd[3 * base + j];
            s_in[2304 + j] = ks[3 * base + j];
        }
        for (int j = tid; j < nblk; j += 256)
            s_in[3072 + j] = reflect_occ[base + j];
    }
    __syncthreads();

    if (tid < nblk) {
        float vx = s_in[3 * tid], vy = s_in[3 * tid + 1], vz = s_in[3 * tid + 2];
        float nx = s_in[768 + 3 * tid], ny = s_in[768 + 3 * tid + 1], nz = s_in[768 + 3 * tid + 2];
        float kdx = s_in[1536 + 3 * tid], kdy = s_in[1536 + 3 * tid + 1], kdz = s_in[1536 + 3 * tid + 2];
        float ks0 = s_in[2304 + 3 * tid], rough = s_in[2304 + 3 * tid + 1], metallic = s_in[2304 + 3 * tid + 2];
        float occ = s_in[3072 + tid];

        // reflect + normalize
        float vdotn = vx * nx + vy * ny + vz * nz;
        float rx = 2.f * vdotn * nx - vx;
        float ry = 2.f * vdotn * ny - vy;
        float rz = 2.f * vdotn * nz - vz;
        float rinv = __builtin_amdgcn_rsqf(fmaxf(rx * rx + ry * ry + rz * rz, 1e-20f));
        rx *= rinv; ry *= rinv; rz *= rinv;

        // diffuse address (lr=4)
        float dtx, dty; int dIdx;
        {
            int face; float u, v;
            cube_face_uv(nx, ny, nz, face, u, v);
            float fx = (u * 0.5f + 0.5f) * 16.f - 0.5f;
            float fy = (v * 0.5f + 0.5f) * 16.f - 0.5f;
            float x0f = floorf(fx), y0f = floorf(fy);
            dtx = fx - x0f; dty = fy - y0f;
            int x0 = min(max((int)x0f, 0), 15);
            int y0 = min(max((int)y0f, 0), 15);
            dIdx = (face << 8) + (y0 << 4) + x0;
        }

        // LUT address
        float ltx, lty; int lutI;
        {
            float NdotV = fmaxf(vdotn, 1e-4f);
            float fx = NdotV * 256.f - 0.5f;
            float fy = rough * 256.f - 0.5f;
            float x0f = floorf(fx), y0f = floorf(fy);
            ltx = fx - x0f; lty = fy - y0f;
            int x0 = min(max((int)x0f, 0), 255);
            int y0 = min(max((int)y0f, 0), 255);
            lutI = (y0 << 8) + x0;
        }

        // mip selection
        const float MINR = 0.08f, MAXR = 0.5f;
        float lo = (fminf(fmaxf(rough, MINR), MAXR) - MINR) * (4.0f / (MAXR - MINR));
        float hi = (fminf(fmaxf(rough, MAXR), 1.0f) - MAXR) * (1.0f / (1.0f - MAXR)) + 4.0f;
        float lvl = fminf(fmaxf((rough < MAXR) ? lo : hi, 0.f), 5.f);
        int l0 = min(max((int)floorf(lvl), 0), 5);
        int l1 = min(l0 + 1, 5);
        float fmip = lvl - (float)l0;

        // spec A address; B derived (same face, half-res coords)
        float atx, aty, btx, bty; int aIdx, bIdx;
        {
            int face; float u, v;
            cube_face_uv(rx, ry, rz, face, u, v);
            int lrA = 9 - l0, lrB = 9 - l1;
            float RA = (float)(1 << lrA);
            float fxA = (u * 0.5f + 0.5f) * RA - 0.5f;
            float fyA = (v * 0.5f + 0.5f) * RA - 0.5f;
            float fxB = (l0 == l1) ? fxA : (fxA + 0.5f) * 0.5f - 0.5f;
            float fyB = (l0 == l1) ? fyA : (fyA + 0.5f) * 0.5f - 0.5f;

            float x0fA = floorf(fxA), y0fA = floorf(fyA);
            atx = fxA - x0fA; aty = fyA - y0fA;
            int WA = 1 << lrA;
            int x0A = min(max((int)x0fA, 0), WA - 1);
            int y0A = min(max((int)y0fA, 0), WA - 1);
            aIdx = (face << (2 * lrA)) + (y0A << lrA) + x0A;

            float x0fB = floorf(fxB), y0fB = floorf(fyB);
            btx = fxB - x0fB; bty = fyB - y0fB;
            int WB = 1 << lrB;
            int x0B = min(max((int)x0fB, 0), WB - 1);
            int y0B = min(max((int)y0fB, 0), WB - 1);
            bIdx = (face << (2 * lrB)) + (y0B << lrB) + x0B;
        }

        static const int OFF[6] = {0, 1572864, 1966080, 2064384, 2088960, 2095104};
        uint4 qA = (q + OFF[l0])[aIdx];
        uint4 qB = (q + OFF[l1])[bIdx];
        uint4 lq = (q + LUT_OFF)[lutI];
        uint4 dq = (q + DIF_OFF)[dIdx];

        float ar, ag, ab_, br, bg, bb;
        gather_q9(qA, atx, aty, ar, ag, ab_);
        gather_q9(qB, btx, bty, br, bg, bb);

        __half2 h00 = *reinterpret_cast<__half2*>(&lq.x);
        __half2 h01 = *reinterpret_cast<__half2*>(&lq.y);
        __half2 h10 = *reinterpret_cast<__half2*>(&lq.z);
        __half2 h11 = *reinterpret_cast<__half2*>(&lq.w);
        float2 c00 = __half22float2(h00), c01 = __half22float2(h01);
        float2 c10 = __half22float2(h10), c11 = __half22float2(h11);
        float lw00 = (1.f - ltx) * (1.f - lty);
        float lw01 = ltx * (1.f - lty);
        float lw10 = (1.f - ltx) * lty;
        float lw11 = ltx * lty;
        float fg0 = c00.x * lw00 + c01.x * lw01 + c10.x * lw10 + c11.x * lw11;
        float fg1 = c00.y * lw00 + c01.y * lw01 + c10.y * lw10 + c11.y * lw11;

        float dfr, dfg, dfb;
        gather_q9(dq, dtx, dty, dfr, dfg, dfb);
        dfr = fmaxf(dfr, 0.f); dfg = fmaxf(dfg, 0.f); dfb = fmaxf(dfb, 0.f);

        float spr = fmaxf(ar * (1.f - fmip) + br * fmip, 0.f);
        float spg = fmaxf(ag * (1.f - fmip) + bg * fmip, 0.f);
        float spb = fmaxf(ab_ * (1.f - fmip) + bb * fmip, 0.f);

        float m = metallic;
        float scx = (1.f - m) * 0.04f + kdx * m;
        float scy = (1.f - m) * 0.04f + kdy * m;
        float scz = (1.f - m) * 0.04f + kdz * m;
        float dcx = kdx * (1.f - m);
        float dcy = kdy * (1.f - m);
        float dcz = kdz * (1.f - m);

        float kds = 1.f - ks0;
        float om = 1.f - occ;
        float shx = dfr * dcx * kds + spr * (scx * fg0 + fg1) * om;
        float shy = dfg * dcy * kds + spg * (scy * fg0 + fg1) * om;
        float shz = dfb * dcz * kds + spb * (scz * fg0 + fg1) * om;

        s_out[3 * tid + 0] = srgb1(fminf(fmaxf(shx, 0.f), 1.f));
        s_out[3 * tid + 1] = srgb1(fminf(fmaxf(shy, 0.f), 1.f));
        s_out[3 * tid + 2] = srgb1(fminf(fmaxf(shz, 0.f), 1.f));
    }
    __syncthreads();

    if (nblk == 256) {
        if (tid < 192)
            ((float4*)(out + 3 * base))[tid] = ((const float4*)s_out)[tid];
    } else {
        for (int j = tid; j < nblk * 3; j += 256)
            out[3 * base + j] = s_out[j];
    }
}

// ---------------- raw-float fallback (ws too small; shouldn't trigger) ----------------
__global__ __launch_bounds__(256)
void envlight_raw(const float* __restrict__ view_dir,
                  const float* __restrict__ normal,
                  const float* __restrict__ kd,
                  const float* __restrict__ ks,
                  const float* __restrict__ reflect_occ,
                  const float* __restrict__ diffuse_map,
                  const float* __restrict__ s0, const float* __restrict__ s1,
                  const float* __restrict__ s2, const float* __restrict__ s3,
                  const float* __restrict__ s4, const float* __restrict__ s5,
                  const float* __restrict__ fg_lut,
                  float* __restrict__ out, int n)
{
    int i = blockIdx.x * blockDim.x + threadIdx.x;
    if (i >= n) return;

    float vx = view_dir[3 * i], vy = view_dir[3 * i + 1], vz = view_dir[3 * i + 2];
    float nx = normal[3 * i],  ny = normal[3 * i + 1],  nz = normal[3 * i + 2];
    float kdx = kd[3 * i], kdy = kd[3 * i + 1], kdz = kd[3 * i + 2];
    float ks0 = ks[3 * i], rough = ks[3 * i + 1], metallic = ks[3 * i + 2];
    float occ = reflect_occ[i];

    float vdotn = vx * nx + vy * ny + vz * nz;
    float rx = 2.f * vdotn * nx - vx;
    float ry = 2.f * vdotn * ny - vy;
    float rz = 2.f * vdotn * nz - vz;
    float rinv = __builtin_amdgcn_rsqf(fmaxf(rx * rx + ry * ry + rz * rz, 1e-20f));
    rx *= rinv; ry *= rinv; rz *= rinv;

    const float* mips[6] = {s0, s1, s2, s3, s4, s5};

    const float MINR = 0.08f, MAXR = 0.5f;
    float lo = (fminf(fmaxf(rough, MINR), MAXR) - MINR) * (4.0f / (MAXR - MINR));
    float hi = (fminf(fmaxf(rough, MAXR), 1.0f) - MAXR) * (1.0f / (1.0f - MAXR)) + 4.0f;
    float lvl = fminf(fmaxf((rough < MAXR) ? lo : hi, 0.f), 5.f);
    int l0 = min(max((int)floorf(lvl), 0), 5);
    int l1 = min(l0 + 1, 5);
    float f = lvl - (float)l0;

    float acc[3][3];
    float dirs[3][3] = {{nx, ny, nz}, {rx, ry, rz}, {rx, ry, rz}};
    int lrs[3] = {4, 9 - l0, 9 - l1};
    const float* texs[3] = {diffuse_map, mips[l0], mips[l1]};
    for (int s = 0; s < 3; ++s) {
        int face; float u, v;
        cube_face_uv(dirs[s][0], dirs[s][1], dirs[s][2], face, u, v);
        int lr = lrs[s], W = 1 << lr;
        float fx = (u * 0.5f + 0.5f) * (float)W - 0.5f;
        float fy = (v * 0.5f + 0.5f) * (float)W - 0.5f;
        float x0f = floorf(fx), y0f = floorf(fy);
        float tx = fx - x0f, ty = fy - y0f;
        int x0 = min(max((int)x0f, 0), W - 1);
        int x1 = min(x0 + 1, W - 1);
        int y0 = min(max((int)y0f, 0), W - 1);
        int y1 = min(y0 + 1, W - 1);
        int base = face << (2 * lr);
        const float* t = texs[s];
        const float* p00 = t + 3 * (base + (y0 << lr) + x0);
        const float* p01 = t + 3 * (base + (y0 << lr) + x1);
        const float* p10 = t + 3 * (base + (y1 << lr) + x0);
        const float* p11 = t + 3 * (base + (y1 << lr) + x1);
        float w00 = (1.f - tx) * (1.f - ty), w01 = tx * (1.f - ty);
        float w10 = (1.f - tx) * ty, w11 = tx * ty;
        for (int c = 0; c < 3; ++c)
            acc[s][c] = p00[c] * w00 + p01[c] * w01 + p10[c] * w10 + p11[c] * w11;
    }

    float NdotV = fmaxf(vdotn, 1e-4f);
    float fx = NdotV * 256.f - 0.5f, fy = rough * 256.f - 0.5f;
    float x0f = floorf(fx), y0f = floorf(fy);
    float tx = fx - x0f, ty = fy - y0f;
    int x0 = min(max((int)x0f, 0), 255);
    int x1 = min(x0 + 1, 255);
    int y0 = min(max((int)y0f, 0), 255);
    int y1 = min(y0 + 1, 255);
    const float2* lut2 = (const float2*)fg_lut;
    float2 c00 = lut2[(y0 << 8) + x0], c01 = lut2[(y0 << 8) + x1];
    float2 c10 = lut2[(y1 << 8) + x0], c11 = lut2[(y1 << 8) + x1];
    float w00 = (1.f - tx) * (1.f - ty), w01 = tx * (1.f - ty);
    float w10 = (1.f - tx) * ty, w11 = tx * ty;
    float fg0 = c00.x * w00 + c01.x * w01 + c10.x * w10 + c11.x * w11;
    float fg1 = c00.y * w00 + c01.y * w01 + c10.y * w10 + c11.y * w11;

    float dfr = fmaxf(acc[0][0], 0.f), dfg = fmaxf(acc[0][1], 0.f), dfb = fmaxf(acc[0][2], 0.f);
    float spr = fmaxf(acc[1][0] * (1.f - f) + acc[2][0] * f, 0.f);
    float spg = fmaxf(acc[1][1] * (1.f - f) + acc[2][1] * f, 0.f);
    float spb = fmaxf(acc[1][2] * (1.f - f) + acc[2][2] * f, 0.f);

    float m = metallic;
    float scx = (1.f - m) * 0.04f + kdx * m;
    float scy = (1.f - m) * 0.04f + kdy * m;
    float scz = (1.f - m) * 0.04f + kdz * m;
    float kds = 1.f - ks0;
    float om = 1.f - occ;
    float shx = dfr * kdx * (1.f - m) * kds + spr * (scx * fg0 + fg1) * om;
    float shy = dfg * kdy * (1.f - m) * kds + spg * (scy * fg0 + fg1) * om;
    float shz = dfb * kdz * (1.f - m) * kds + spb * (scz * fg0 + fg1) * om;

    out[3 * i + 0] = srgb1(fminf(fmaxf(shx, 0.f), 1.f));
    out[3 * i + 1] = srgb1(fminf(fmaxf(shy, 0.f), 1.f));
    out[3 * i + 2] = srgb1(fminf(fmaxf(shz, 0.f), 1.f));
}

extern "C" void kernel_launch(void* const* d_in, const int* in_sizes, int n_in,
                              void* d_out, int out_size, void* d_ws, size_t ws_size,
                              hipStream_t stream) {
    const float* view_dir    = (const float*)d_in[0];
    const float* normal      = (const float*)d_in[1];
    const float* kd          = (const float*)d_in[2];
    const float* ks          = (const float*)d_in[3];
    const float* reflect_occ = (const float*)d_in[4];
    const float* diffuse_map = (const float*)d_in[5];
    const float* s0          = (const float*)d_in[6];
    const float* s1          = (const float*)d_in[7];
    const float* s2          = (const float*)d_in[8];
    const float* s3          = (const float*)d_in[9];
    const float* s4          = (const float*)d_in[10];
    const float* s5          = (const float*)d_in[11];
    const float* fg_lut      = (const float*)d_in[12];
    float* out = (float*)d_out;

    int n = in_sizes[0] / 3;
    int block = 256;
    int grid = (n + block - 1) / block;
    const size_t NEED_Q = (size_t)ALL_QUADS * 16;   // ~34.6 MB

    if (ws_size >= NEED_Q) {
        uint4* q = (uint4*)d_ws;
        repack_all<<<(ALL_QUADS + 255) / 256, 256, 0, stream>>>(
            s0, s1, s2, s3, s4, s5, diffuse_map, (const float2*)fg_lut, q);
        envlight_lds<<<grid, block, 0, stream>>>(
            view_dir, normal, kd, ks, reflect_occ, q, out, n);
    } else {
        envlight_raw<<<grid, block, 0, stream>>>(
            view_dir, normal, kd, ks, reflect_occ, diffuse_map,
            s0, s1, s2, s3, s4, s5, fg_lut, out, n);
    }
}